// Round 1
// baseline (248.040 us; speedup 1.0000x reference)
//
#include <hip/hip_runtime.h>
#include <math.h>

// DiffKS: time-varying 7-tap sparse IIR.
// y[n] = x[n] + sum_{i=0..6} block_i[n] * y[n - zc[n] - i],  zc in [37,97].
// Min lag 37 => 37 consecutive samples are independent -> wave-parallel chunks.

#define BATCH 16
#define CHUNK 37   // guaranteed min dependency distance (f0 >= 40 -> zc >= 37)

// ---------------- Kernel 1: per-sample coefficients ----------------
// ws layout: [B*N][8] floats = {block0..block6, (float)zc}
__global__ __launch_bounds__(256) void diffks_coeff(
    const float* __restrict__ f0, const float* __restrict__ lb,
    float* __restrict__ cw, int total) {
  int idx = blockIdx.x * blockDim.x + threadIdx.x;
  if (idx >= total) return;
  float g  = 0.99f * lb[2 * idx];
  float p  = lb[2 * idx + 1];
  float b0 = g * (1.0f - p);
  float a1 = g * p;
  float f0c = f0[idx] - a1 / (b0 + a1 + 1e-7f);
  int   zc  = (int)floorf(f0c) - 2;
  float alpha = f0c - (float)zc;
  // Lagrange order-5 weights: w_j = prod_{m!=j}(alpha-m) / prod_{m!=j}(j-m)
  float u0 = alpha;
  float u1 = alpha - 1.0f;
  float u2 = alpha - 2.0f;
  float u3 = alpha - 3.0f;
  float u4 = alpha - 4.0f;
  float u5 = alpha - 5.0f;
  float w0 = u1 * u2 * u3 * u4 * u5 * (-1.0f / 120.0f);
  float w1 = u0 * u2 * u3 * u4 * u5 * ( 1.0f /  24.0f);
  float w2 = u0 * u1 * u3 * u4 * u5 * (-1.0f /  12.0f);
  float w3 = u0 * u1 * u2 * u4 * u5 * ( 1.0f /  12.0f);
  float w4 = u0 * u1 * u2 * u3 * u5 * (-1.0f /  24.0f);
  float w5 = u0 * u1 * u2 * u3 * u4 * ( 1.0f / 120.0f);
  float4 lo, hi;
  lo.x = b0 * w0;                   // block0
  lo.y = fmaf(b0, w1, a1 * w0);     // block1
  lo.z = fmaf(b0, w2, a1 * w1);     // block2
  lo.w = fmaf(b0, w3, a1 * w2);     // block3
  hi.x = fmaf(b0, w4, a1 * w3);     // block4
  hi.y = fmaf(b0, w5, a1 * w4);     // block5
  hi.z = a1 * w5;                   // block6
  hi.w = (float)zc;                 // exact for small ints
  float4* out4 = (float4*)cw;
  out4[2 * idx]     = lo;
  out4[2 * idx + 1] = hi;
}

// ---------------- Kernel 2: sequential scan, 1 wave per batch ----------------
// LDS ring of 256 floats holds the live history window (max lag 103 + chunk 37
// + slack < 256). Zero-init provides the zero initial state: slots aliasing
// negative positions are only overwritten at iterations >= 4, after their last
// read at iterations <= 2.
__global__ __launch_bounds__(64) void diffks_scan(
    const float* __restrict__ x, const float* __restrict__ cw,
    float* __restrict__ y, int N) {
  const int b    = blockIdx.x;
  const int lane = threadIdx.x;
  __shared__ float ring[256];
  ring[lane]       = 0.0f;
  ring[lane + 64]  = 0.0f;
  ring[lane + 128] = 0.0f;
  ring[lane + 192] = 0.0f;
  __syncthreads();

  const float4* c4 = (const float4*)(cw + (size_t)b * N * 8);
  const float*  xb = x + (size_t)b * N;
  float*        yb = y + (size_t)b * N;

  const int nIter = (N + CHUNK - 1) / CHUNK;   // 443
  const int nPad  = (nIter + 3) & ~3;          // 444
  const bool act  = (lane < CHUNK);

  // 4-deep register prefetch ring (statically indexed via unroll)
  float4 Lo[4], Hi[4];
  float  Xv[4];
#pragma unroll
  for (int d = 0; d < 4; ++d) {
    int n = d * CHUNK + lane;
    if (act && n < N) {
      Lo[d] = c4[2 * n];
      Hi[d] = c4[2 * n + 1];
      Xv[d] = xb[n];
    }
  }

  for (int tb = 0; tb < nPad; tb += 4) {
#pragma unroll
    for (int u = 0; u < 4; ++u) {
      const int t = tb + u;
      const int n = t * CHUNK + lane;
      float4 lo = Lo[u], hi = Hi[u];
      float  xv = Xv[u];
      // prefetch iteration t+4 into this stage (off the critical path)
      {
        int np = (t + 4) * CHUNK + lane;
        if (act && np < N) {
          Lo[u] = c4[2 * np];
          Hi[u] = c4[2 * np + 1];
          Xv[u] = xb[np];
        }
      }
      if (act && n < N) {
        const int q  = n - (int)hi.w;   // tap0 position
        const float t0 = ring[(q    ) & 255];
        const float t1 = ring[(q - 1) & 255];
        const float t2 = ring[(q - 2) & 255];
        const float t3 = ring[(q - 3) & 255];
        const float t4 = ring[(q - 4) & 255];
        const float t5 = ring[(q - 5) & 255];
        const float t6 = ring[(q - 6) & 255];
        // balanced FMA tree (depth ~4)
        const float s0 = fmaf(lo.x, t0, xv);
        const float s1 = fmaf(lo.y, t1, lo.z * t2);
        const float s2 = fmaf(lo.w, t3, hi.x * t4);
        const float s3 = fmaf(hi.y, t5, hi.z * t6);
        const float yv = (s0 + s1) + (s2 + s3);
        ring[n & 255] = yv;   // writes (>=37t) never alias reads (<=37t-1) this iter
        yb[n] = yv;
      }
      __syncthreads();  // publish iter t history before iter t+1 reads
    }
  }
}

extern "C" void kernel_launch(void* const* d_in, const int* in_sizes, int n_in,
                              void* d_out, int out_size, void* d_ws, size_t ws_size,
                              hipStream_t stream) {
  const float* f0 = (const float*)d_in[0];
  const float* x  = (const float*)d_in[1];
  const float* lb = (const float*)d_in[2];
  float* out = (float*)d_out;

  const int total = in_sizes[0];        // B*N = 262144
  const int N     = total / BATCH;      // 16384
  float* cw = (float*)d_ws;             // needs total*8*4 = 8 MB

  diffks_coeff<<<(total + 255) / 256, 256, 0, stream>>>(f0, lb, cw, total);
  diffks_scan<<<BATCH, 64, 0, stream>>>(x, cw, out, N);
}

// Round 2
// 205.824 us; speedup vs baseline: 1.2051x; 1.2051x over previous
//
#include <hip/hip_runtime.h>
#include <math.h>

// DiffKS: time-varying 7-tap sparse IIR.
// y[n] = x[n] + sum_{i=0..6} block_i[n] * y[n - zc[n] - i],  zc in [37,97].
// Min lag 37 => 37 consecutive samples are independent -> wave-parallel chunks.
// Single wave per batch => no __syncthreads needed (lockstep + in-order DS).

#define BATCH 16
#define CHUNK 37   // guaranteed min dependency distance (f0 >= 40 -> zc >= 37)

// ---------------- Kernel 1: per-sample coefficients ----------------
// ws layout: [B*N][8] floats = {block0..block6, int_bits(ring read base)}
// ring read base = (n - 6 - zc) & 255 : dword index of y[n-zc-6] in the ring.
__global__ __launch_bounds__(256) void diffks_coeff(
    const float* __restrict__ f0, const float* __restrict__ lb,
    float* __restrict__ cw, int total, int Nmask) {
  int idx = blockIdx.x * blockDim.x + threadIdx.x;
  if (idx >= total) return;
  float g  = 0.99f * lb[2 * idx];
  float p  = lb[2 * idx + 1];
  float b0 = g * (1.0f - p);
  float a1 = g * p;
  float f0c = f0[idx] - a1 / (b0 + a1 + 1e-7f);
  int   zc  = (int)floorf(f0c) - 2;
  float alpha = f0c - (float)zc;
  // Lagrange order-5 weights
  float u0 = alpha;
  float u1 = alpha - 1.0f;
  float u2 = alpha - 2.0f;
  float u3 = alpha - 3.0f;
  float u4 = alpha - 4.0f;
  float u5 = alpha - 5.0f;
  float w0 = u1 * u2 * u3 * u4 * u5 * (-1.0f / 120.0f);
  float w1 = u0 * u2 * u3 * u4 * u5 * ( 1.0f /  24.0f);
  float w2 = u0 * u1 * u3 * u4 * u5 * (-1.0f /  12.0f);
  float w3 = u0 * u1 * u2 * u4 * u5 * ( 1.0f /  12.0f);
  float w4 = u0 * u1 * u2 * u3 * u5 * (-1.0f /  24.0f);
  float w5 = u0 * u1 * u2 * u3 * u4 * ( 1.0f / 120.0f);
  float4 lo, hi;
  lo.x = b0 * w0;                   // block0
  lo.y = fmaf(b0, w1, a1 * w0);     // block1
  lo.z = fmaf(b0, w2, a1 * w1);     // block2
  lo.w = fmaf(b0, w3, a1 * w2);     // block3
  hi.x = fmaf(b0, w4, a1 * w3);     // block4
  hi.y = fmaf(b0, w5, a1 * w4);     // block5
  hi.z = a1 * w5;                   // block6
  int n = idx & Nmask;              // sample index within batch (N pow2)
  hi.w = __int_as_float((n - 6 - zc) & 255);  // precomputed ring read base
  float4* out4 = (float4*)cw;
  out4[2 * idx]     = lo;
  out4[2 * idx + 1] = hi;
}

// ---------------- Kernel 2: sequential scan, 1 wave per batch ----------------
// Mirrored 512-float LDS ring: sample n written at (n&255) and (n&255)+256, so
// the 7 taps y[n-zc-6 .. n-zc] are the contiguous dwords base..base+6 (<=261).
// Zero-init provides the zero initial state (slots for negative positions are
// overwritten only after their last read).
__global__ __launch_bounds__(64) void diffks_scan(
    const float* __restrict__ x, const float* __restrict__ cw,
    float* __restrict__ y, int N) {
  const int b    = blockIdx.x;
  const int lane = threadIdx.x;
  __shared__ float ring[512];
#pragma unroll
  for (int i = 0; i < 8; ++i) ring[lane + 64 * i] = 0.0f;
  __builtin_amdgcn_wave_barrier();
  asm volatile("" ::: "memory");

  const float4* __restrict__ c4 = (const float4*)(cw + (size_t)b * N * 8);
  const float*  __restrict__ xb = x + (size_t)b * N;
  float*        __restrict__ yb = y + (size_t)b * N;
  const bool act = (lane < CHUNK);

  // 4-deep register prefetch ring (statically indexed via unroll-by-4)
  float4 Lo[4], Hi[4];
  float  Xv[4];
  int    Wb[4];   // ring write dword slot
#pragma unroll
  for (int d = 0; d < 4; ++d) {
    int n = d * CHUNK + lane;
    if (act) {
      Lo[d] = c4[2 * n];
      Hi[d] = c4[2 * n + 1];
      Xv[d] = xb[n];
    }
    Wb[d] = n & 255;
  }

  // Main loop: consume t = 0..435; prefetch t+4 <= 439 so n+4*CHUNK < N always
  // (439*37+36 = 16279 < 16384) -> no bounds checks anywhere in the hot loop.
  for (int tb = 0; tb < 436; tb += 4) {
#pragma unroll
    for (int u = 0; u < 4; ++u) {
      const int n = (tb + u) * CHUNK + lane;
      float4 lo = Lo[u], hi = Hi[u];
      float  xv = Xv[u];
      const int wslot = Wb[u];
      // prefetch iteration t+4 into this stage (off the critical path)
      if (act) {
        const int np = n + 4 * CHUNK;
        Lo[u] = c4[2 * np];
        Hi[u] = c4[2 * np + 1];
        Xv[u] = xb[np];
      }
      Wb[u] = (wslot + 4 * CHUNK) & 255;
      if (act) {
        const int base = __float_as_int(hi.w);     // precomputed (n-6-zc)&255
        const float r0 = ring[base + 0];           // y[n-zc-6]
        const float r1 = ring[base + 1];
        const float r2 = ring[base + 2];
        const float r3 = ring[base + 3];
        const float r4 = ring[base + 4];
        const float r5 = ring[base + 5];
        const float r6 = ring[base + 6];           // y[n-zc]
        const float s0 = fmaf(lo.x, r6, xv);
        const float s1 = fmaf(lo.y, r5, lo.z * r4);
        const float s2 = fmaf(lo.w, r3, hi.x * r2);
        const float s3 = fmaf(hi.y, r1, hi.z * r0);
        const float yv = (s0 + s1) + (s2 + s3);
        ring[wslot]       = yv;   // writes (pos >= 37t) never alias this
        ring[wslot + 256] = yv;   // iter's reads (pos <= 37t-1)
        yb[n] = yv;
      }
      // single wave: lockstep + in-order DS pipeline replace __syncthreads.
      // Fences pin program order in the compiler; emit no instructions.
      __builtin_amdgcn_wave_barrier();
      asm volatile("" ::: "memory");
    }
  }

  // Tail: t = 436..442, direct loads with bounds checks.
  for (int t = 436; t < 443; ++t) {
    const int n = t * CHUNK + lane;
    if (act && n < N) {
      const float4 lo = c4[2 * n];
      const float4 hi = c4[2 * n + 1];
      const float  xv = xb[n];
      const int base = __float_as_int(hi.w);
      const float r0 = ring[base + 0];
      const float r1 = ring[base + 1];
      const float r2 = ring[base + 2];
      const float r3 = ring[base + 3];
      const float r4 = ring[base + 4];
      const float r5 = ring[base + 5];
      const float r6 = ring[base + 6];
      const float s0 = fmaf(lo.x, r6, xv);
      const float s1 = fmaf(lo.y, r5, lo.z * r4);
      const float s2 = fmaf(lo.w, r3, hi.x * r2);
      const float s3 = fmaf(hi.y, r1, hi.z * r0);
      const float yv = (s0 + s1) + (s2 + s3);
      ring[n & 255]         = yv;
      ring[(n & 255) + 256] = yv;
      yb[n] = yv;
    }
    __builtin_amdgcn_wave_barrier();
    asm volatile("" ::: "memory");
  }
}

extern "C" void kernel_launch(void* const* d_in, const int* in_sizes, int n_in,
                              void* d_out, int out_size, void* d_ws, size_t ws_size,
                              hipStream_t stream) {
  const float* f0 = (const float*)d_in[0];
  const float* x  = (const float*)d_in[1];
  const float* lb = (const float*)d_in[2];
  float* out = (float*)d_out;

  const int total = in_sizes[0];        // B*N = 262144
  const int N     = total / BATCH;      // 16384 (pow2)
  float* cw = (float*)d_ws;             // needs total*8*4 = 8 MB

  diffks_coeff<<<(total + 255) / 256, 256, 0, stream>>>(f0, lb, cw, total, N - 1);
  diffks_scan<<<BATCH, 64, 0, stream>>>(x, cw, out, N);
}

// Round 3
// 119.644 us; speedup vs baseline: 2.0732x; 1.7203x over previous
//
#include <hip/hip_runtime.h>
#include <math.h>

// DiffKS: time-varying 7-tap sparse IIR.
//   y[n] = x[n] + sum_{i=0..6} block_i[n] * y[n - zc[n] - i],  zc in [37,97].
// Max lag 103 -> 103-sample state. Linear => segmented superposition:
//   phase1: per (batch,segment) run 103 unit-state + 1 particular IIRs (shared
//           taps, run-interleaved in LDS) -> T[103x103], p_last[103]
//   phase2: serial state composition across segments (tiny matvecs)
//   phase3: exact re-run of each segment with known incoming state (28 iters)

#define B_    16
#define N_    16384
#define S_    16
#define NSEG  1024
#define NITER 28      // ceil(1024/37)
#define RUNS  104     // 103 unit columns + 1 particular
#define RG    26      // run groups of 4 (float4)
#define CHUNK 37      // guaranteed min dependency distance (zc >= 37)

#define CW_FLOATS (B_ * N_ * 8)          // 2,097,152
#define TG_FLOATS (B_ * S_ * RUNS * RUNS) // 2,768,896
#define ST_FLOATS (B_ * S_ * RUNS)        // 26,624

// ---- shared coeff math (exact copy of the proven round-2 formulas) ----
__device__ __forceinline__ void diffks_coeffs(float f0v, float lbg, float lbp,
                                              int n, float4& lo, float4& hi) {
  float g  = 0.99f * lbg;
  float p  = lbp;
  float b0 = g * (1.0f - p);
  float a1 = g * p;
  float f0c = f0v - a1 / (b0 + a1 + 1e-7f);
  int   zc  = (int)floorf(f0c) - 2;
  float alpha = f0c - (float)zc;
  float u0 = alpha;
  float u1 = alpha - 1.0f;
  float u2 = alpha - 2.0f;
  float u3 = alpha - 3.0f;
  float u4 = alpha - 4.0f;
  float u5 = alpha - 5.0f;
  float w0 = u1 * u2 * u3 * u4 * u5 * (-1.0f / 120.0f);
  float w1 = u0 * u2 * u3 * u4 * u5 * ( 1.0f /  24.0f);
  float w2 = u0 * u1 * u3 * u4 * u5 * (-1.0f /  12.0f);
  float w3 = u0 * u1 * u2 * u4 * u5 * ( 1.0f /  12.0f);
  float w4 = u0 * u1 * u2 * u3 * u5 * (-1.0f /  24.0f);
  float w5 = u0 * u1 * u2 * u3 * u4 * ( 1.0f / 120.0f);
  lo.x = b0 * w0;                   // block0
  lo.y = fmaf(b0, w1, a1 * w0);     // block1
  lo.z = fmaf(b0, w2, a1 * w1);     // block2
  lo.w = fmaf(b0, w3, a1 * w2);     // block3
  hi.x = fmaf(b0, w4, a1 * w3);     // block4
  hi.y = fmaf(b0, w5, a1 * w4);     // block5
  hi.z = a1 * w5;                   // block6
  hi.w = __int_as_float((n - 6 - zc) & 255);   // ring read base (mod-256 slot)
}

// =================== Phase 1: T matrices + particular tails ===================
// grid 256 (= b*16+s), block 1024. LDS ~140 KB (1 WG/CU).
__global__ __launch_bounds__(1024) void diffks_phase1(
    const float* __restrict__ f0, const float* __restrict__ lb,
    const float* __restrict__ x, float* __restrict__ cw,
    float* __restrict__ Tg) {
  const int bs = blockIdx.x;
  const int b  = bs >> 4, s = bs & 15;
  const int n0 = s << 10;
  const int tid = threadIdx.x;

  __shared__ float4 hist4[256 * RG];   // [row 0..255][run-group 0..25]
  __shared__ float4 stA[NSEG], stB[NSEG];
  __shared__ float  stX[NSEG];

  // zero history
  for (int i = tid; i < 256 * RG; i += 1024) hist4[i] = float4{0, 0, 0, 0};

  // stage coefficients (computed from f0/lb; also written to cw for phase 3)
  {
    const int n = n0 + tid;                 // blockDim == NSEG
    const size_t gi = (size_t)b * N_ + n;
    float4 lo, hi;
    diffks_coeffs(f0[gi], lb[2 * gi], lb[2 * gi + 1], n, lo, hi);
    stA[tid] = lo; stB[tid] = hi; stX[tid] = x[gi];
    float4* c4 = (float4*)cw;
    c4[2 * gi]     = lo;
    c4[2 * gi + 1] = hi;
  }
  __syncthreads();

  // unit initial states: position n0-1-k -> row 103-k holds e_k (k=0..102)
  if (tid >= 1 && tid <= 103) {
    const int row = tid, r = 103 - tid;
    ((float*)&hist4[row * RG + (r >> 2)])[r & 3] = 1.0f;
  }
  __syncthreads();

  const int  l   = tid / RG;          // time-lane 0..36 (>=37 idle)
  const int  rg  = tid - l * RG;      // run-group 0..25
  const bool actT = (l < CHUNK);

  for (int t = 0; t < NITER; ++t) {
    const int prel = t * CHUNK + l;
    if (actT && prel < NSEG) {
      const float4 lo = stA[prel];
      const float4 hi = stB[prel];
      const int base1 = (__float_as_int(hi.w) + 104) & 255;  // row of oldest tap
      float4 acc = {0.0f, 0.0f, 0.0f,
                    (rg == RG - 1) ? stX[prel] : 0.0f};      // run 103 gets x
      // tap m (m=0 oldest) pairs with block_{6-m}
      const float cm0 = hi.z, cm1 = hi.y, cm2 = hi.x, cm3 = lo.w,
                  cm4 = lo.z, cm5 = lo.y, cm6 = lo.x;
      const float c[7] = {cm0, cm1, cm2, cm3, cm4, cm5, cm6};
#pragma unroll
      for (int m = 0; m < 7; ++m) {
        const int row = (base1 + m) & 255;
        const float4 v = hist4[row * RG + rg];
        acc.x = fmaf(c[m], v.x, acc.x);
        acc.y = fmaf(c[m], v.y, acc.y);
        acc.z = fmaf(c[m], v.z, acc.z);
        acc.w = fmaf(c[m], v.w, acc.w);
      }
      hist4[((prel + 104) & 255) * RG + rg] = acc;
    }
    __syncthreads();
  }

  // emit Tg[bs][r][j] = run r's output at position Nseg-1-j (row (103-j)&255)
  float* T = Tg + (size_t)bs * RUNS * RUNS;
  for (int idx = tid; idx < RUNS * RUNS; idx += 1024) {
    const int r = idx / RUNS;
    const int j = idx - r * RUNS;
    const int row = (103 - j) & 255;        // j=103 -> row 0 (unused by phase2)
    T[idx] = ((float*)&hist4[row * RG + (r >> 2)])[r & 3];
  }
}

// =================== Phase 2: serial state composition ===================
// grid 16 (batch), block 128. state_{s+1}[j] = p[j] + sum_k T[k][j]*state[k]
__global__ __launch_bounds__(128) void diffks_phase2(
    const float* __restrict__ Tg, float* __restrict__ states) {
  const int b = blockIdx.x;
  const int j = threadIdx.x;
  __shared__ float cur[RUNS];
  if (j < RUNS) cur[j] = 0.0f;
  __syncthreads();
  for (int s = 0; s < S_; ++s) {
    if (j < RUNS) states[((size_t)b * S_ + s) * RUNS + j] = cur[j];
    const float* __restrict__ T = Tg + ((size_t)b * S_ + s) * RUNS * RUNS;
    float acc = 0.0f;
    if (j < 103) {
      const float* __restrict__ Tj = T + j;
      float a0 = 0.0f, a1 = 0.0f, a2 = 0.0f, a3 = 0.0f;
      int k = 0;
      for (; k + 3 < 103; k += 4) {
        a0 = fmaf(Tj[(k + 0) * RUNS], cur[k + 0], a0);
        a1 = fmaf(Tj[(k + 1) * RUNS], cur[k + 1], a1);
        a2 = fmaf(Tj[(k + 2) * RUNS], cur[k + 2], a2);
        a3 = fmaf(Tj[(k + 3) * RUNS], cur[k + 3], a3);
      }
      for (; k < 103; ++k) a0 = fmaf(Tj[k * RUNS], cur[k], a0);
      acc = ((a0 + a1) + (a2 + a3)) + Tj[103 * RUNS];   // + particular tail
    }
    __syncthreads();
    if (j < 103) cur[j] = acc;
    __syncthreads();
  }
}

// =================== Phase 3: exact per-segment re-run ===================
// grid 256 (= b*16+s), block 64 (one wave). All hot-loop traffic is LDS.
__global__ __launch_bounds__(64) void diffks_phase3(
    const float* __restrict__ x, const float* __restrict__ cw,
    const float* __restrict__ states, float* __restrict__ y) {
  const int bs = blockIdx.x;
  const int b  = bs >> 4, s = bs & 15;
  const int n0 = s << 10;
  const int lane = threadIdx.x;

  __shared__ float  ring[512];     // mirrored mod-256 ring
  __shared__ float4 sC[2 * NSEG];  // interleaved lo/hi per sample (32 KB)
  __shared__ float4 sX4[NSEG / 4];
  __shared__ float4 sY4[NSEG / 4];

#pragma unroll
  for (int i = 0; i < 8; ++i) ring[lane + 64 * i] = 0.0f;

  // bulk-stage coeffs + x (latency-tolerant 16-deep batches)
  const float4* __restrict__ c4 = ((const float4*)cw) + (size_t)(b * N_ + n0) * 2;
  const float4* __restrict__ x4 = (const float4*)(x + (size_t)b * N_ + n0);
  {
    float4 tmp[16];
#pragma unroll
    for (int half = 0; half < 2; ++half) {
      const int base = half * 1024;
#pragma unroll
      for (int q = 0; q < 16; ++q) tmp[q] = c4[base + 64 * q + lane];
#pragma unroll
      for (int q = 0; q < 16; ++q) sC[base + 64 * q + lane] = tmp[q];
    }
#pragma unroll
    for (int q = 0; q < 4; ++q) tmp[q] = x4[64 * q + lane];
#pragma unroll
    for (int q = 0; q < 4; ++q) sX4[64 * q + lane] = tmp[q];
  }
  __builtin_amdgcn_wave_barrier();
  asm volatile("" ::: "memory");

  // incoming state: ring[(n0-1-k)&255] = st[k] (n0 % 256 == 0) + mirror
  const float* __restrict__ st = states + (size_t)bs * RUNS;
  {
    const float v = st[lane];                 // k = lane (0..63)
    if (lane < 103) { ring[255 - lane] = v; ring[511 - lane] = v; }
    if (lane < 39) {
      const float v2 = st[lane + 64];         // k = 64..102
      ring[191 - lane] = v2; ring[447 - lane] = v2;
    }
  }
  __builtin_amdgcn_wave_barrier();
  asm volatile("" ::: "memory");

  const bool actL = (lane < CHUNK);
  for (int t = 0; t < NITER; ++t) {
    const int prel = t * CHUNK + lane;
    if (actL && prel < NSEG) {
      const float4 lo = sC[2 * prel];
      const float4 hi = sC[2 * prel + 1];
      const float  xv = ((const float*)sX4)[prel];
      const int base = __float_as_int(hi.w);   // (n-6-zc)&255
      const float r0 = ring[base + 0];
      const float r1 = ring[base + 1];
      const float r2 = ring[base + 2];
      const float r3 = ring[base + 3];
      const float r4 = ring[base + 4];
      const float r5 = ring[base + 5];
      const float r6 = ring[base + 6];
      const float s0 = fmaf(lo.x, r6, xv);
      const float s1 = fmaf(lo.y, r5, lo.z * r4);
      const float s2 = fmaf(lo.w, r3, hi.x * r2);
      const float s3 = fmaf(hi.y, r1, hi.z * r0);
      const float yv = (s0 + s1) + (s2 + s3);
      const int w = prel & 255;
      ring[w]       = yv;
      ring[w + 256] = yv;
      ((float*)sY4)[prel] = yv;
    }
    __builtin_amdgcn_wave_barrier();
    asm volatile("" ::: "memory");
  }

  // flush outputs
  float4* __restrict__ yb = (float4*)(y + (size_t)b * N_ + n0);
#pragma unroll
  for (int q = 0; q < 4; ++q) yb[64 * q + lane] = sY4[64 * q + lane];
}

// =================== Fallback (proven round-2 path) ===================
__global__ __launch_bounds__(256) void diffks_coeff_fb(
    const float* __restrict__ f0, const float* __restrict__ lb,
    float* __restrict__ cw, int total, int Nmask) {
  int idx = blockIdx.x * blockDim.x + threadIdx.x;
  if (idx >= total) return;
  float4 lo, hi;
  diffks_coeffs(f0[idx], lb[2 * idx], lb[2 * idx + 1], idx & Nmask, lo, hi);
  float4* out4 = (float4*)cw;
  out4[2 * idx]     = lo;
  out4[2 * idx + 1] = hi;
}

__global__ __launch_bounds__(64) void diffks_scan_fb(
    const float* __restrict__ x, const float* __restrict__ cw,
    float* __restrict__ y, int N) {
  const int b    = blockIdx.x;
  const int lane = threadIdx.x;
  __shared__ float ring[512];
#pragma unroll
  for (int i = 0; i < 8; ++i) ring[lane + 64 * i] = 0.0f;
  __builtin_amdgcn_wave_barrier();
  asm volatile("" ::: "memory");
  const float4* __restrict__ c4 = (const float4*)(cw + (size_t)b * N * 8);
  const float*  __restrict__ xb = x + (size_t)b * N;
  float*        __restrict__ yb = y + (size_t)b * N;
  const bool act = (lane < CHUNK);
  const int nIter = (N + CHUNK - 1) / CHUNK;
  for (int t = 0; t < nIter; ++t) {
    const int n = t * CHUNK + lane;
    if (act && n < N) {
      const float4 lo = c4[2 * n];
      const float4 hi = c4[2 * n + 1];
      const float  xv = xb[n];
      const int base = __float_as_int(hi.w);
      const float r0 = ring[base + 0];
      const float r1 = ring[base + 1];
      const float r2 = ring[base + 2];
      const float r3 = ring[base + 3];
      const float r4 = ring[base + 4];
      const float r5 = ring[base + 5];
      const float r6 = ring[base + 6];
      const float s0 = fmaf(lo.x, r6, xv);
      const float s1 = fmaf(lo.y, r5, lo.z * r4);
      const float s2 = fmaf(lo.w, r3, hi.x * r2);
      const float s3 = fmaf(hi.y, r1, hi.z * r0);
      const float yv = (s0 + s1) + (s2 + s3);
      ring[n & 255]         = yv;
      ring[(n & 255) + 256] = yv;
      yb[n] = yv;
    }
    __builtin_amdgcn_wave_barrier();
    asm volatile("" ::: "memory");
  }
}

extern "C" void kernel_launch(void* const* d_in, const int* in_sizes, int n_in,
                              void* d_out, int out_size, void* d_ws, size_t ws_size,
                              hipStream_t stream) {
  const float* f0 = (const float*)d_in[0];
  const float* x  = (const float*)d_in[1];
  const float* lb = (const float*)d_in[2];
  float* out = (float*)d_out;

  const int total = in_sizes[0];
  float* cw = (float*)d_ws;
  const size_t need = (size_t)(CW_FLOATS + TG_FLOATS + ST_FLOATS) * 4;

  if (total == B_ * N_ && ws_size >= need) {
    float* Tg = cw + CW_FLOATS;
    float* st = Tg + TG_FLOATS;
    diffks_phase1<<<B_ * S_, 1024, 0, stream>>>(f0, lb, x, cw, Tg);
    diffks_phase2<<<B_, 128, 0, stream>>>(Tg, st);
    diffks_phase3<<<B_ * S_, 64, 0, stream>>>(x, cw, st, out);
  } else {
    const int N = total / B_;
    diffks_coeff_fb<<<(total + 255) / 256, 256, 0, stream>>>(f0, lb, cw, total, N - 1);
    diffks_scan_fb<<<B_, 64, 0, stream>>>(x, cw, out, N);
  }
}